// Round 1
// baseline (2356.356 us; speedup 1.0000x reference)
//
#include <hip/hip_runtime.h>

#define N_NODES 50000
#define N_EDGES 600000
#define D 128

// One thread per (edge, 4-feature chunk): 600000*32 threads.
// Gathers float4 from x[src], atomicAdd's into agg[dst].
// Lane0 of each edge also bumps the in-degree counter (first layer only).
__global__ __launch_bounds__(256) void scatter_kernel(
    const float* __restrict__ x,
    const int* __restrict__ ei,
    float* __restrict__ agg,
    float* __restrict__ cnt /* null for layer 2 */)
{
    int idx = blockIdx.x * blockDim.x + threadIdx.x;
    int e = idx >> 5;
    if (e >= N_EDGES) return;
    int f = (idx & 31) << 2;
    int src = ei[e];
    int dst = ei[N_EDGES + e];
    const float4 v = *(const float4*)(x + (size_t)src * D + f);
    float* a = agg + (size_t)dst * D + f;
    atomicAdd(a + 0, v.x);
    atomicAdd(a + 1, v.y);
    atomicAdd(a + 2, v.z);
    atomicAdd(a + 3, v.w);
    if (cnt != nullptr && (idx & 31) == 0) atomicAdd(cnt + dst, 1.0f);
}

// 8 nodes per 256-thread block. thread j = tid&127 computes output feature j
// for 4 nodes (half = tid>>7 picks which 4). mean/x rows staged in LDS
// (broadcast reads, conflict-free); W read from global (L1/L2-hot, reused x8
// within the block).
template <bool RELU>
__global__ __launch_bounds__(256) void node_kernel(
    const float* __restrict__ agg, const float* __restrict__ cnt,
    const float* __restrict__ xin, const float* __restrict__ Wl,
    const float* __restrict__ Wr, const float* __restrict__ bias,
    float* __restrict__ out)
{
    __shared__ float ms[8][D];
    __shared__ float xs[8][D];
    const int j = threadIdx.x & (D - 1);
    const int half = threadIdx.x >> 7;   // 0..1
    const int base = blockIdx.x * 8;     // 50000 = 6250*8, no remainder

    for (int i = half; i < 8; i += 2) {
        int nn = base + i;
        float c = fmaxf(cnt[nn], 1.0f);
        ms[i][j] = agg[(size_t)nn * D + j] / c;
        xs[i][j] = xin[(size_t)nn * D + j];
    }
    __syncthreads();

    const float bj = bias[j];
    float acc0 = bj, acc1 = bj, acc2 = bj, acc3 = bj;
    const int i0 = half * 4;

#pragma unroll 4
    for (int k = 0; k < D; ++k) {
        float wl = Wl[k * D + j];
        float wr = Wr[k * D + j];
        acc0 += ms[i0 + 0][k] * wl + xs[i0 + 0][k] * wr;
        acc1 += ms[i0 + 1][k] * wl + xs[i0 + 1][k] * wr;
        acc2 += ms[i0 + 2][k] * wl + xs[i0 + 2][k] * wr;
        acc3 += ms[i0 + 3][k] * wl + xs[i0 + 3][k] * wr;
    }

    float r0 = RELU ? fmaxf(acc0, 0.0f) : acc0;
    float r1 = RELU ? fmaxf(acc1, 0.0f) : acc1;
    float r2 = RELU ? fmaxf(acc2, 0.0f) : acc2;
    float r3 = RELU ? fmaxf(acc3, 0.0f) : acc3;
    out[(size_t)(base + i0 + 0) * D + j] = r0;
    out[(size_t)(base + i0 + 1) * D + j] = r1;
    out[(size_t)(base + i0 + 2) * D + j] = r2;
    out[(size_t)(base + i0 + 3) * D + j] = r3;
}

extern "C" void kernel_launch(void* const* d_in, const int* in_sizes, int n_in,
                              void* d_out, int out_size, void* d_ws, size_t ws_size,
                              hipStream_t stream) {
    const float* x   = (const float*)d_in[0];
    const int*   ei  = (const int*)d_in[1];   // [2, E] — row0 src, row1 dst
    const float* Wl1 = (const float*)d_in[2];
    const float* Wr1 = (const float*)d_in[3];
    const float* b1  = (const float*)d_in[4];
    const float* Wl2 = (const float*)d_in[5];
    const float* Wr2 = (const float*)d_in[6];
    const float* b2  = (const float*)d_in[7];
    float* out = (float*)d_out;

    // workspace layout: agg [N*D] | cnt [N] | h [N*D]  (~51.4 MB)
    float* agg = (float*)d_ws;
    float* cnt = agg + (size_t)N_NODES * D;
    float* h   = cnt + N_NODES;

    const size_t aggBytes = (size_t)N_NODES * D * sizeof(float);
    const int scatterBlocks = (N_EDGES * 32 + 255) / 256;

    // ---- layer 1 ----
    hipMemsetAsync(agg, 0, aggBytes + (size_t)N_NODES * sizeof(float), stream); // agg + cnt
    scatter_kernel<<<scatterBlocks, 256, 0, stream>>>(x, ei, agg, cnt);
    node_kernel<true><<<N_NODES / 8, 256, 0, stream>>>(agg, cnt, x, Wl1, Wr1, b1, h);

    // ---- layer 2 ----
    hipMemsetAsync(agg, 0, aggBytes, stream);
    scatter_kernel<<<scatterBlocks, 256, 0, stream>>>(h, ei, agg, nullptr);
    node_kernel<false><<<N_NODES / 8, 256, 0, stream>>>(agg, cnt, h, Wl2, Wr2, b2, out);
}

// Round 2
// 487.566 us; speedup vs baseline: 4.8329x; 4.8329x over previous
//
#include <hip/hip_runtime.h>

#define N_NODES 50000
#define N_EDGES 600000
#define D 128
#define SCAN_THREADS 1024

// ---------- CSR construction (counting sort by dst) ----------

__global__ __launch_bounds__(256) void hist_kernel(const int* __restrict__ ei,
                                                   int* __restrict__ counts) {
    int e = blockIdx.x * blockDim.x + threadIdx.x;
    if (e < N_EDGES) atomicAdd(&counts[ei[N_EDGES + e]], 1);
}

// Single-block exclusive scan of counts[0..N). Writes:
//   offsets[0]=0, offsets[i+1]=inclusive(i)  (segment bounds)
//   counts[i] = exclusive(i)                 (becomes the scatter cursor)
__global__ __launch_bounds__(SCAN_THREADS) void scan_kernel(int* __restrict__ counts,
                                                            int* __restrict__ offsets) {
    __shared__ int wsum[16];
    __shared__ int woff[16];
    __shared__ int carry_s;
    const int tid = threadIdx.x;
    const int lane = tid & 63;
    const int wid = tid >> 6;
    if (tid == 0) { carry_s = 0; offsets[0] = 0; }
    __syncthreads();
    for (int base = 0; base < N_NODES; base += SCAN_THREADS) {
        int i = base + tid;
        int c = (i < N_NODES) ? counts[i] : 0;
        int acc = c;
        #pragma unroll
        for (int d = 1; d < 64; d <<= 1) {
            int v = __shfl_up(acc, d, 64);
            if (lane >= d) acc += v;
        }
        if (lane == 63) wsum[wid] = acc;
        __syncthreads();
        if (wid == 0) {
            int v = (lane < 16) ? wsum[lane] : 0;
            #pragma unroll
            for (int d = 1; d < 16; d <<= 1) {
                int t = __shfl_up(v, d, 64);
                if (lane >= d) v += t;
            }
            if (lane < 16) woff[lane] = v;  // inclusive scan of wave sums
        }
        __syncthreads();
        int carry = carry_s;
        int wprefix = (wid > 0) ? woff[wid - 1] : 0;
        int excl = carry + wprefix + (acc - c);
        if (i < N_NODES) {
            counts[i] = excl;
            offsets[i + 1] = excl + c;
        }
        __syncthreads();
        if (tid == SCAN_THREADS - 1) carry_s = carry + woff[15];
        __syncthreads();
    }
}

__global__ __launch_bounds__(256) void build_csr_kernel(const int* __restrict__ ei,
                                                        int* __restrict__ cursor,
                                                        int* __restrict__ sorted_src) {
    int e = blockIdx.x * blockDim.x + threadIdx.x;
    if (e < N_EDGES) {
        int src = ei[e];
        int dst = ei[N_EDGES + e];
        int pos = atomicAdd(&cursor[dst], 1);
        sorted_src[pos] = src;
    }
}

// ---------- mean aggregation via CSR (no atomics) ----------
// 32 lanes per node (float4 over 128 features), 8 nodes per 256-block.
__global__ __launch_bounds__(256) void agg_kernel(const float* __restrict__ x,
                                                  const int* __restrict__ offsets,
                                                  const int* __restrict__ sorted_src,
                                                  float* __restrict__ mean) {
    const int lane = threadIdx.x & 31;
    const int node = blockIdx.x * 8 + (threadIdx.x >> 5);  // 50000 = 6250*8
    int beg = offsets[node], end = offsets[node + 1];
    float4 acc = {0.f, 0.f, 0.f, 0.f};
    for (int e = beg; e < end; ++e) {
        int s = sorted_src[e];
        float4 v = ((const float4*)x)[s * 32 + lane];
        acc.x += v.x; acc.y += v.y; acc.z += v.z; acc.w += v.w;
    }
    float inv = 1.0f / fmaxf((float)(end - beg), 1.0f);
    acc.x *= inv; acc.y *= inv; acc.z *= inv; acc.w *= inv;
    ((float4*)mean)[node * 32 + lane] = acc;
}

// ---------- node-side dense: out = mean@Wl + x@Wr + b (optional relu) ----------
template <bool RELU>
__global__ __launch_bounds__(256) void node_kernel(
    const float* __restrict__ mean, const float* __restrict__ xin,
    const float* __restrict__ Wl, const float* __restrict__ Wr,
    const float* __restrict__ bias, float* __restrict__ out)
{
    __shared__ float ms[8][D];
    __shared__ float xs[8][D];
    const int j = threadIdx.x & (D - 1);
    const int half = threadIdx.x >> 7;
    const int base = blockIdx.x * 8;  // 50000 = 6250*8

    for (int i = half; i < 8; i += 2) {
        int nn = base + i;
        ms[i][j] = mean[(size_t)nn * D + j];
        xs[i][j] = xin[(size_t)nn * D + j];
    }
    __syncthreads();

    const float bj = bias[j];
    float acc0 = bj, acc1 = bj, acc2 = bj, acc3 = bj;
    const int i0 = half * 4;

#pragma unroll 4
    for (int k = 0; k < D; ++k) {
        float wl = Wl[k * D + j];
        float wr = Wr[k * D + j];
        acc0 += ms[i0 + 0][k] * wl + xs[i0 + 0][k] * wr;
        acc1 += ms[i0 + 1][k] * wl + xs[i0 + 1][k] * wr;
        acc2 += ms[i0 + 2][k] * wl + xs[i0 + 2][k] * wr;
        acc3 += ms[i0 + 3][k] * wl + xs[i0 + 3][k] * wr;
    }

    out[(size_t)(base + i0 + 0) * D + j] = RELU ? fmaxf(acc0, 0.f) : acc0;
    out[(size_t)(base + i0 + 1) * D + j] = RELU ? fmaxf(acc1, 0.f) : acc1;
    out[(size_t)(base + i0 + 2) * D + j] = RELU ? fmaxf(acc2, 0.f) : acc2;
    out[(size_t)(base + i0 + 3) * D + j] = RELU ? fmaxf(acc3, 0.f) : acc3;
}

extern "C" void kernel_launch(void* const* d_in, const int* in_sizes, int n_in,
                              void* d_out, int out_size, void* d_ws, size_t ws_size,
                              hipStream_t stream) {
    const float* x   = (const float*)d_in[0];
    const int*   ei  = (const int*)d_in[1];
    const float* Wl1 = (const float*)d_in[2];
    const float* Wr1 = (const float*)d_in[3];
    const float* b1  = (const float*)d_in[4];
    const float* Wl2 = (const float*)d_in[5];
    const float* Wr2 = (const float*)d_in[6];
    const float* b2  = (const float*)d_in[7];
    float* out = (float*)d_out;

    // ws layout: mean [N*D] f32 (16B-aligned at ws start) | counts [N] | offsets [N+1] | srcs [E]
    float* mean    = (float*)d_ws;
    int*   counts  = (int*)(mean + (size_t)N_NODES * D);
    int*   offsets = counts + N_NODES;
    int*   srcs    = offsets + N_NODES + 1;
    // total ≈ 25.6 MB + 2.8 MB

    const int eBlocks = (N_EDGES + 255) / 256;

    // ---- build CSR once (shared by both layers) ----
    hipMemsetAsync(counts, 0, N_NODES * sizeof(int), stream);
    hist_kernel<<<eBlocks, 256, 0, stream>>>(ei, counts);
    scan_kernel<<<1, SCAN_THREADS, 0, stream>>>(counts, offsets);
    build_csr_kernel<<<eBlocks, 256, 0, stream>>>(ei, counts, srcs);

    // ---- layer 1 ----  (h is written into d_out)
    agg_kernel<<<N_NODES / 8, 256, 0, stream>>>(x, offsets, srcs, mean);
    node_kernel<true><<<N_NODES / 8, 256, 0, stream>>>(mean, x, Wl1, Wr1, b1, out);

    // ---- layer 2 ----  (reads h from d_out, overwrites d_out; per-block rows
    // are staged in LDS before the overwrite, and blocks touch disjoint rows)
    agg_kernel<<<N_NODES / 8, 256, 0, stream>>>(out, offsets, srcs, mean);
    node_kernel<false><<<N_NODES / 8, 256, 0, stream>>>(mean, out, Wl2, Wr2, b2, out);
}

// Round 3
// 301.737 us; speedup vs baseline: 7.8093x; 1.6159x over previous
//
#include <hip/hip_runtime.h>
#include <hip/hip_bf16.h>

#define N_NODES 50000
#define N_EDGES 600000
#define D 128
#define K2 256  // 2*D
#define SCAN_THREADS 1024

typedef __bf16 bf16x8 __attribute__((ext_vector_type(8)));
typedef float  f32x16 __attribute__((ext_vector_type(16)));

__device__ __forceinline__ unsigned short f32_to_bf16_rne(float f) {
    unsigned int u = __builtin_bit_cast(unsigned int, f);
    unsigned int r = (u + 0x7fffu + ((u >> 16) & 1u)) >> 16;
    return (unsigned short)r;
}
__device__ __forceinline__ float bfl(unsigned int u) { return __builtin_bit_cast(float, u << 16); }
__device__ __forceinline__ float bfh(unsigned int u) { return __builtin_bit_cast(float, u & 0xffff0000u); }

// ---------- CSR construction (counting sort by dst) ----------
__global__ __launch_bounds__(256) void hist_kernel(const int* __restrict__ ei,
                                                   int* __restrict__ counts) {
    int e = blockIdx.x * blockDim.x + threadIdx.x;
    if (e < N_EDGES) atomicAdd(&counts[ei[N_EDGES + e]], 1);
}

__global__ __launch_bounds__(SCAN_THREADS) void scan_kernel(int* __restrict__ counts,
                                                            int* __restrict__ offsets) {
    __shared__ int wsum[16];
    __shared__ int woff[16];
    __shared__ int carry_s;
    const int tid = threadIdx.x;
    const int lane = tid & 63;
    const int wid = tid >> 6;
    if (tid == 0) { carry_s = 0; offsets[0] = 0; }
    __syncthreads();
    for (int base = 0; base < N_NODES; base += SCAN_THREADS) {
        int i = base + tid;
        int c = (i < N_NODES) ? counts[i] : 0;
        int acc = c;
        #pragma unroll
        for (int d = 1; d < 64; d <<= 1) {
            int v = __shfl_up(acc, d, 64);
            if (lane >= d) acc += v;
        }
        if (lane == 63) wsum[wid] = acc;
        __syncthreads();
        if (wid == 0) {
            int v = (lane < 16) ? wsum[lane] : 0;
            #pragma unroll
            for (int d = 1; d < 16; d <<= 1) {
                int t = __shfl_up(v, d, 64);
                if (lane >= d) v += t;
            }
            if (lane < 16) woff[lane] = v;
        }
        __syncthreads();
        int carry = carry_s;
        int wprefix = (wid > 0) ? woff[wid - 1] : 0;
        int excl = carry + wprefix + (acc - c);
        if (i < N_NODES) {
            counts[i] = excl;
            offsets[i + 1] = excl + c;
        }
        __syncthreads();
        if (tid == SCAN_THREADS - 1) carry_s = carry + woff[15];
        __syncthreads();
    }
}

__global__ __launch_bounds__(256) void build_csr_kernel(const int* __restrict__ ei,
                                                        int* __restrict__ cursor,
                                                        int* __restrict__ sorted_src) {
    int e = blockIdx.x * blockDim.x + threadIdx.x;
    if (e < N_EDGES) {
        int src = ei[e];
        int dst = ei[N_EDGES + e];
        int pos = atomicAdd(&cursor[dst], 1);
        sorted_src[pos] = src;
    }
}

// ---------- x -> bf16 into A[:, 128:256] ----------
__global__ __launch_bounds__(256) void convert_x_kernel(const float* __restrict__ x,
                                                        unsigned short* __restrict__ A) {
    int idx = blockIdx.x * blockDim.x + threadIdx.x;  // 50000*16 exactly
    int node = idx >> 4, g = idx & 15;
    const float4* xp = (const float4*)(x + (size_t)node * D + g * 8);
    float4 v0 = xp[0], v1 = xp[1];
    ushort4 o0, o1;
    o0.x = f32_to_bf16_rne(v0.x); o0.y = f32_to_bf16_rne(v0.y);
    o0.z = f32_to_bf16_rne(v0.z); o0.w = f32_to_bf16_rne(v0.w);
    o1.x = f32_to_bf16_rne(v1.x); o1.y = f32_to_bf16_rne(v1.y);
    o1.z = f32_to_bf16_rne(v1.z); o1.w = f32_to_bf16_rne(v1.w);
    ushort4* dst = (ushort4*)(A + (size_t)node * K2 + D + g * 8);
    dst[0] = o0; dst[1] = o1;
}

// ---------- W -> WT bf16: WT[layer][n][k], k<128 -> Wl[k][n], k>=128 -> Wr[k-128][n] ----------
__global__ __launch_bounds__(256) void prep_w_kernel(const float* __restrict__ Wl1,
                                                     const float* __restrict__ Wr1,
                                                     const float* __restrict__ Wl2,
                                                     const float* __restrict__ Wr2,
                                                     unsigned short* __restrict__ WT) {
    int idx = blockIdx.x * blockDim.x + threadIdx.x;  // 2*128*256 = 65536 exactly
    int layer = idx >> 15, rem = idx & 32767;
    int n = rem >> 8, k = rem & 255;
    const float* Wl = layer ? Wl2 : Wl1;
    const float* Wr = layer ? Wr2 : Wr1;
    float v = (k < D) ? Wl[k * D + n] : Wr[(k - D) * D + n];
    WT[((size_t)layer << 15) + n * K2 + k] = f32_to_bf16_rne(v);
}

// ---------- mean aggregation: gather bf16 x-half rows, write bf16 mean-half ----------
__global__ __launch_bounds__(256) void agg_kernel(unsigned short* A,
                                                  const int* __restrict__ offsets,
                                                  const int* __restrict__ srcs) {
    const int lane = threadIdx.x & 15;
    const int node = blockIdx.x * 16 + (threadIdx.x >> 4);  // 50000 = 3125*16
    int beg = offsets[node], end = offsets[node + 1];
    float a0 = 0, a1 = 0, a2 = 0, a3 = 0, a4 = 0, a5 = 0, a6 = 0, a7 = 0;
    const uint4* Ax = (const uint4*)A;  // row = 32 uint4, x-half at +16
    int e = beg;
    for (; e + 1 < end; e += 2) {
        int s0 = srcs[e], s1 = srcs[e + 1];
        uint4 v = Ax[(size_t)s0 * 32 + 16 + lane];
        uint4 w = Ax[(size_t)s1 * 32 + 16 + lane];
        a0 += bfl(v.x); a1 += bfh(v.x); a2 += bfl(v.y); a3 += bfh(v.y);
        a4 += bfl(v.z); a5 += bfh(v.z); a6 += bfl(v.w); a7 += bfh(v.w);
        a0 += bfl(w.x); a1 += bfh(w.x); a2 += bfl(w.y); a3 += bfh(w.y);
        a4 += bfl(w.z); a5 += bfh(w.z); a6 += bfl(w.w); a7 += bfh(w.w);
    }
    if (e < end) {
        uint4 v = Ax[(size_t)srcs[e] * 32 + 16 + lane];
        a0 += bfl(v.x); a1 += bfh(v.x); a2 += bfl(v.y); a3 += bfh(v.y);
        a4 += bfl(v.z); a5 += bfh(v.z); a6 += bfl(v.w); a7 += bfh(v.w);
    }
    float inv = 1.0f / fmaxf((float)(end - beg), 1.0f);
    ushort4 o0, o1;
    o0.x = f32_to_bf16_rne(a0 * inv); o0.y = f32_to_bf16_rne(a1 * inv);
    o0.z = f32_to_bf16_rne(a2 * inv); o0.w = f32_to_bf16_rne(a3 * inv);
    o1.x = f32_to_bf16_rne(a4 * inv); o1.y = f32_to_bf16_rne(a5 * inv);
    o1.z = f32_to_bf16_rne(a6 * inv); o1.w = f32_to_bf16_rne(a7 * inv);
    ushort4* dst = (ushort4*)(A + (size_t)node * K2 + lane * 8);
    dst[0] = o0; dst[1] = o1;
}

// ---------- GEMM: out = A @ WT^T + b   (A: [N,256] bf16, WT: [128,256] bf16) ----------
// One wave per block, 32 rows x 128 cols per wave, MFMA 32x32x16 bf16, K=256.
// A-frag: lane holds A[m=lane&31][k0 + (lane>>5)*8 + j]; B-frag mirrors with n=lane&31.
// C/D: col=lane&31, row=(reg&3)+8*(reg>>2)+4*(lane>>5)  [measured m74/m101].
template <bool RELU, bool OUT_BF16>
__global__ __launch_bounds__(64) void gemm_kernel(const unsigned short* A,
                                                  const unsigned short* __restrict__ WT,
                                                  const float* __restrict__ bias,
                                                  float* outf,
                                                  unsigned short* outh) {
    const int lane = threadIdx.x;
    const int r0 = blockIdx.x * 32;
    const int m = lane & 31;
    const int kg = (lane >> 5) * 8;  // 0 or 8
    int row = r0 + m;
    if (row >= N_NODES) row = N_NODES - 1;  // clamp: duplicate reads, stores masked

    const uint4* ap  = (const uint4*)(A + (size_t)row * K2 + kg);          // +2 per k-step
    const uint4* bp0 = (const uint4*)(WT + (size_t)(0 * 32 + m) * K2 + kg);
    const uint4* bp1 = (const uint4*)(WT + (size_t)(1 * 32 + m) * K2 + kg);
    const uint4* bp2 = (const uint4*)(WT + (size_t)(2 * 32 + m) * K2 + kg);
    const uint4* bp3 = (const uint4*)(WT + (size_t)(3 * 32 + m) * K2 + kg);

    f32x16 acc0 = {}, acc1 = {}, acc2 = {}, acc3 = {};

    #pragma unroll 4
    for (int s = 0; s < 16; ++s) {
        bf16x8 a = __builtin_bit_cast(bf16x8, ap[s * 2]);
        acc0 = __builtin_amdgcn_mfma_f32_32x32x16_bf16(a, __builtin_bit_cast(bf16x8, bp0[s * 2]), acc0, 0, 0, 0);
        acc1 = __builtin_amdgcn_mfma_f32_32x32x16_bf16(a, __builtin_bit_cast(bf16x8, bp1[s * 2]), acc1, 0, 0, 0);
        acc2 = __builtin_amdgcn_mfma_f32_32x32x16_bf16(a, __builtin_bit_cast(bf16x8, bp2[s * 2]), acc2, 0, 0, 0);
        acc3 = __builtin_amdgcn_mfma_f32_32x32x16_bf16(a, __builtin_bit_cast(bf16x8, bp3[s * 2]), acc3, 0, 0, 0);
    }

    const int halfadd = (lane >> 5) * 4;
    f32x16 accs[4] = {acc0, acc1, acc2, acc3};
    #pragma unroll
    for (int c = 0; c < 4; ++c) {
        int col = c * 32 + m;
        float bc = bias[col];
        #pragma unroll
        for (int r = 0; r < 16; ++r) {
            int rw = r0 + (r & 3) + 8 * (r >> 2) + halfadd;
            if (rw < N_NODES) {
                float v = accs[c][r] + bc;
                if (RELU) v = fmaxf(v, 0.0f);
                if (OUT_BF16) outh[(size_t)rw * K2 + D + col] = f32_to_bf16_rne(v);
                else outf[(size_t)rw * D + col] = v;
            }
        }
    }
}

extern "C" void kernel_launch(void* const* d_in, const int* in_sizes, int n_in,
                              void* d_out, int out_size, void* d_ws, size_t ws_size,
                              hipStream_t stream) {
    const float* x   = (const float*)d_in[0];
    const int*   ei  = (const int*)d_in[1];
    const float* Wl1 = (const float*)d_in[2];
    const float* Wr1 = (const float*)d_in[3];
    const float* b1  = (const float*)d_in[4];
    const float* Wl2 = (const float*)d_in[5];
    const float* Wr2 = (const float*)d_in[6];
    const float* b2  = (const float*)d_in[7];
    float* out = (float*)d_out;

    // ws: A [50000][256] bf16 | WT [2][128][256] bf16 | counts [N] | offsets [N+1] | srcs [E]
    unsigned short* A  = (unsigned short*)d_ws;
    unsigned short* WT = A + (size_t)N_NODES * K2;
    int* counts  = (int*)(WT + 2 * D * K2);
    int* offsets = counts + N_NODES;
    int* srcs    = offsets + N_NODES + 1;
    // total ~28.5 MB

    const int eBlocks = (N_EDGES + 255) / 256;
    const int gemmBlocks = (N_NODES + 31) / 32;

    // CSR (shared by both layers)
    hipMemsetAsync(counts, 0, N_NODES * sizeof(int), stream);
    hist_kernel<<<eBlocks, 256, 0, stream>>>(ei, counts);
    scan_kernel<<<1, SCAN_THREADS, 0, stream>>>(counts, offsets);
    build_csr_kernel<<<eBlocks, 256, 0, stream>>>(ei, counts, srcs);

    // operand prep
    convert_x_kernel<<<N_NODES * 16 / 256, 256, 0, stream>>>(x, A);
    prep_w_kernel<<<65536 / 256, 256, 0, stream>>>(Wl1, Wr1, Wl2, Wr2, WT);

    // layer 1: agg -> A[:,0:128]; gemm -> h bf16 into A[:,128:256] (in place, rows disjoint)
    agg_kernel<<<N_NODES / 16, 256, 0, stream>>>(A, offsets, srcs);
    gemm_kernel<true, true><<<gemmBlocks, 64, 0, stream>>>(A, WT, b1, nullptr, A);

    // layer 2: agg over h; gemm -> fp32 d_out
    agg_kernel<<<N_NODES / 16, 256, 0, stream>>>(A, offsets, srcs);
    gemm_kernel<false, false><<<gemmBlocks, 64, 0, stream>>>(A, WT + (size_t)D * K2, b2, out, nullptr);
}

// Round 4
// 262.324 us; speedup vs baseline: 8.9826x; 1.1502x over previous
//
#include <hip/hip_runtime.h>
#include <hip/hip_bf16.h>

#define N_NODES 50000
#define N_EDGES 600000
#define D 128
#define K2 256  // 2*D
#define SCAN_BLK 1024               // elements per scan block
#define NB_SCAN ((N_NODES + SCAN_BLK - 1) / SCAN_BLK)  // 49

typedef __bf16 bf16x8 __attribute__((ext_vector_type(8)));
typedef float  f32x16 __attribute__((ext_vector_type(16)));

__device__ __forceinline__ unsigned short f32_to_bf16_rne(float f) {
    unsigned int u = __builtin_bit_cast(unsigned int, f);
    unsigned int r = (u + 0x7fffu + ((u >> 16) & 1u)) >> 16;
    return (unsigned short)r;
}
__device__ __forceinline__ float bfl(unsigned int u) { return __builtin_bit_cast(float, u << 16); }
__device__ __forceinline__ float bfh(unsigned int u) { return __builtin_bit_cast(float, u & 0xffff0000u); }

// ---------- CSR construction (counting sort by dst) ----------
__global__ __launch_bounds__(256) void hist_kernel(const int* __restrict__ ei,
                                                   int* __restrict__ counts) {
    int e = blockIdx.x * blockDim.x + threadIdx.x;
    if (e < N_EDGES) atomicAdd(&counts[ei[N_EDGES + e]], 1);
}

// ---- 3-phase parallel exclusive scan of counts[0..N) ----
// Phase 1: per-block sums (256 thr x 4 elems = 1024/block)
__global__ __launch_bounds__(256) void scan_p1(const int* __restrict__ counts,
                                               int* __restrict__ bsum) {
    __shared__ int wsum[4];
    const int tid = threadIdx.x;
    const int lane = tid & 63, wid = tid >> 6;
    int i0 = blockIdx.x * SCAN_BLK + tid * 4;
    int t = 0;
    #pragma unroll
    for (int k = 0; k < 4; ++k) if (i0 + k < N_NODES) t += counts[i0 + k];
    int acc = t;
    #pragma unroll
    for (int d = 1; d < 64; d <<= 1) {
        int v = __shfl_up(acc, d, 64);
        if (lane >= d) acc += v;
    }
    if (lane == 63) wsum[wid] = acc;
    __syncthreads();
    if (tid == 0) bsum[blockIdx.x] = wsum[0] + wsum[1] + wsum[2] + wsum[3];
}

// Phase 2: one wave scans the NB_SCAN block sums -> exclusive prefixes
__global__ __launch_bounds__(64) void scan_p2(const int* __restrict__ bsum,
                                              int* __restrict__ bpre) {
    int lane = threadIdx.x;
    int v = (lane < NB_SCAN) ? bsum[lane] : 0;
    int acc = v;
    #pragma unroll
    for (int d = 1; d < 64; d <<= 1) {
        int t = __shfl_up(acc, d, 64);
        if (lane >= d) acc += t;
    }
    if (lane < NB_SCAN) bpre[lane] = acc - v;
}

// Phase 3: block-local exclusive scan + block prefix; write cursor + offsets
__global__ __launch_bounds__(256) void scan_p3(int* __restrict__ counts,
                                               const int* __restrict__ bpre,
                                               int* __restrict__ offsets) {
    __shared__ int wsum[4];
    const int tid = threadIdx.x;
    const int lane = tid & 63, wid = tid >> 6;
    int i0 = blockIdx.x * SCAN_BLK + tid * 4;
    int c[4];
    int t = 0;
    #pragma unroll
    for (int k = 0; k < 4; ++k) {
        c[k] = (i0 + k < N_NODES) ? counts[i0 + k] : 0;
        t += c[k];
    }
    int acc = t;
    #pragma unroll
    for (int d = 1; d < 64; d <<= 1) {
        int v = __shfl_up(acc, d, 64);
        if (lane >= d) acc += v;
    }
    if (lane == 63) wsum[wid] = acc;
    __syncthreads();
    if (tid == 0) {
        int s = 0;
        #pragma unroll
        for (int w = 0; w < 4; ++w) { int v = wsum[w]; wsum[w] = s; s += v; }
    }
    __syncthreads();
    int excl = bpre[blockIdx.x] + wsum[wid] + (acc - t);
    #pragma unroll
    for (int k = 0; k < 4; ++k) {
        if (i0 + k < N_NODES) {
            counts[i0 + k] = excl;                 // scatter cursor
            offsets[i0 + k + 1] = excl + c[k];     // segment end
        }
        excl += c[k];
    }
    if (blockIdx.x == 0 && tid == 0) offsets[0] = 0;
}

__global__ __launch_bounds__(256) void build_csr_kernel(const int* __restrict__ ei,
                                                        int* __restrict__ cursor,
                                                        int* __restrict__ sorted_src) {
    int e = blockIdx.x * blockDim.x + threadIdx.x;
    if (e < N_EDGES) {
        int src = ei[e];
        int dst = ei[N_EDGES + e];
        int pos = atomicAdd(&cursor[dst], 1);
        sorted_src[pos] = src;
    }
}

// ---------- x -> bf16 into A[:, 128:256] ----------
__global__ __launch_bounds__(256) void convert_x_kernel(const float* __restrict__ x,
                                                        unsigned short* __restrict__ A) {
    int idx = blockIdx.x * blockDim.x + threadIdx.x;  // 50000*16 exactly
    int node = idx >> 4, g = idx & 15;
    const float4* xp = (const float4*)(x + (size_t)node * D + g * 8);
    float4 v0 = xp[0], v1 = xp[1];
    ushort4 o0, o1;
    o0.x = f32_to_bf16_rne(v0.x); o0.y = f32_to_bf16_rne(v0.y);
    o0.z = f32_to_bf16_rne(v0.z); o0.w = f32_to_bf16_rne(v0.w);
    o1.x = f32_to_bf16_rne(v1.x); o1.y = f32_to_bf16_rne(v1.y);
    o1.z = f32_to_bf16_rne(v1.z); o1.w = f32_to_bf16_rne(v1.w);
    ushort4* dst = (ushort4*)(A + (size_t)node * K2 + D + g * 8);
    dst[0] = o0; dst[1] = o1;
}

// ---------- W -> WT bf16: WT[layer][n][k], k<128 -> Wl[k][n], k>=128 -> Wr[k-128][n] ----------
__global__ __launch_bounds__(256) void prep_w_kernel(const float* __restrict__ Wl1,
                                                     const float* __restrict__ Wr1,
                                                     const float* __restrict__ Wl2,
                                                     const float* __restrict__ Wr2,
                                                     unsigned short* __restrict__ WT) {
    int idx = blockIdx.x * blockDim.x + threadIdx.x;  // 2*128*256 = 65536 exactly
    int layer = idx >> 15, rem = idx & 32767;
    int n = rem >> 8, k = rem & 255;
    const float* Wl = layer ? Wl2 : Wl1;
    const float* Wr = layer ? Wr2 : Wr1;
    float v = (k < D) ? Wl[k * D + n] : Wr[(k - D) * D + n];
    WT[((size_t)layer << 15) + n * K2 + k] = f32_to_bf16_rne(v);
}

// ---------- mean aggregation: gather bf16 x-half rows, write bf16 mean-half ----------
__global__ __launch_bounds__(256) void agg_kernel(unsigned short* A,
                                                  const int* __restrict__ offsets,
                                                  const int* __restrict__ srcs) {
    const int lane = threadIdx.x & 15;
    const int node = blockIdx.x * 16 + (threadIdx.x >> 4);  // 50000 = 3125*16
    int beg = offsets[node], end = offsets[node + 1];
    float a0 = 0, a1 = 0, a2 = 0, a3 = 0, a4 = 0, a5 = 0, a6 = 0, a7 = 0;
    const uint4* Ax = (const uint4*)A;  // row = 32 uint4, x-half at +16
    int e = beg;
    for (; e + 1 < end; e += 2) {
        int s0 = srcs[e], s1 = srcs[e + 1];
        uint4 v = Ax[(size_t)s0 * 32 + 16 + lane];
        uint4 w = Ax[(size_t)s1 * 32 + 16 + lane];
        a0 += bfl(v.x); a1 += bfh(v.x); a2 += bfl(v.y); a3 += bfh(v.y);
        a4 += bfl(v.z); a5 += bfh(v.z); a6 += bfl(v.w); a7 += bfh(v.w);
        a0 += bfl(w.x); a1 += bfh(w.x); a2 += bfl(w.y); a3 += bfh(w.y);
        a4 += bfl(w.z); a5 += bfh(w.z); a6 += bfl(w.w); a7 += bfh(w.w);
    }
    if (e < end) {
        uint4 v = Ax[(size_t)srcs[e] * 32 + 16 + lane];
        a0 += bfl(v.x); a1 += bfh(v.x); a2 += bfl(v.y); a3 += bfh(v.y);
        a4 += bfl(v.z); a5 += bfh(v.z); a6 += bfl(v.w); a7 += bfh(v.w);
    }
    float inv = 1.0f / fmaxf((float)(end - beg), 1.0f);
    ushort4 o0, o1;
    o0.x = f32_to_bf16_rne(a0 * inv); o0.y = f32_to_bf16_rne(a1 * inv);
    o0.z = f32_to_bf16_rne(a2 * inv); o0.w = f32_to_bf16_rne(a3 * inv);
    o1.x = f32_to_bf16_rne(a4 * inv); o1.y = f32_to_bf16_rne(a5 * inv);
    o1.z = f32_to_bf16_rne(a6 * inv); o1.w = f32_to_bf16_rne(a7 * inv);
    ushort4* dst = (ushort4*)(A + (size_t)node * K2 + lane * 8);
    dst[0] = o0; dst[1] = o1;
}

// ---------- GEMM: out = A @ WT^T + b   (A: [N,256] bf16, WT: [128,256] bf16) ----------
// One wave per block, 32 rows x 128 cols, MFMA 32x32x16 bf16, K=256.
// C/D: col=lane&31, row=(reg&3)+8*(reg>>2)+4*(lane>>5)  [measured m74/m101].
template <bool RELU, bool OUT_BF16>
__global__ __launch_bounds__(64) void gemm_kernel(const unsigned short* A,
                                                  const unsigned short* __restrict__ WT,
                                                  const float* __restrict__ bias,
                                                  float* outf,
                                                  unsigned short* outh) {
    const int lane = threadIdx.x;
    const int r0 = blockIdx.x * 32;
    const int m = lane & 31;
    const int kg = (lane >> 5) * 8;  // 0 or 8
    int row = r0 + m;
    if (row >= N_NODES) row = N_NODES - 1;  // clamp: duplicate reads, stores masked

    const uint4* ap  = (const uint4*)(A + (size_t)row * K2 + kg);
    const uint4* bp0 = (const uint4*)(WT + (size_t)(0 * 32 + m) * K2 + kg);
    const uint4* bp1 = (const uint4*)(WT + (size_t)(1 * 32 + m) * K2 + kg);
    const uint4* bp2 = (const uint4*)(WT + (size_t)(2 * 32 + m) * K2 + kg);
    const uint4* bp3 = (const uint4*)(WT + (size_t)(3 * 32 + m) * K2 + kg);

    f32x16 acc0 = {}, acc1 = {}, acc2 = {}, acc3 = {};

    #pragma unroll 4
    for (int s = 0; s < 16; ++s) {
        bf16x8 a = __builtin_bit_cast(bf16x8, ap[s * 2]);
        acc0 = __builtin_amdgcn_mfma_f32_32x32x16_bf16(a, __builtin_bit_cast(bf16x8, bp0[s * 2]), acc0, 0, 0, 0);
        acc1 = __builtin_amdgcn_mfma_f32_32x32x16_bf16(a, __builtin_bit_cast(bf16x8, bp1[s * 2]), acc1, 0, 0, 0);
        acc2 = __builtin_amdgcn_mfma_f32_32x32x16_bf16(a, __builtin_bit_cast(bf16x8, bp2[s * 2]), acc2, 0, 0, 0);
        acc3 = __builtin_amdgcn_mfma_f32_32x32x16_bf16(a, __builtin_bit_cast(bf16x8, bp3[s * 2]), acc3, 0, 0, 0);
    }

    const int halfadd = (lane >> 5) * 4;
    f32x16 accs[4] = {acc0, acc1, acc2, acc3};
    #pragma unroll
    for (int c = 0; c < 4; ++c) {
        int col = c * 32 + m;
        float bc = bias[col];
        #pragma unroll
        for (int r = 0; r < 16; ++r) {
            int rw = r0 + (r & 3) + 8 * (r >> 2) + halfadd;
            if (rw < N_NODES) {
                float v = accs[c][r] + bc;
                if (RELU) v = fmaxf(v, 0.0f);
                if (OUT_BF16) outh[(size_t)rw * K2 + D + col] = f32_to_bf16_rne(v);
                else outf[(size_t)rw * D + col] = v;
            }
        }
    }
}

extern "C" void kernel_launch(void* const* d_in, const int* in_sizes, int n_in,
                              void* d_out, int out_size, void* d_ws, size_t ws_size,
                              hipStream_t stream) {
    const float* x   = (const float*)d_in[0];
    const int*   ei  = (const int*)d_in[1];
    const float* Wl1 = (const float*)d_in[2];
    const float* Wr1 = (const float*)d_in[3];
    const float* b1  = (const float*)d_in[4];
    const float* Wl2 = (const float*)d_in[5];
    const float* Wr2 = (const float*)d_in[6];
    const float* b2  = (const float*)d_in[7];
    float* out = (float*)d_out;

    // ws: A [50000][256] bf16 | WT [2][128][256] bf16 | counts [N] | offsets [N+1] |
    //     srcs [E] | bsum [64] | bpre [64]
    unsigned short* A  = (unsigned short*)d_ws;
    unsigned short* WT = A + (size_t)N_NODES * K2;
    int* counts  = (int*)(WT + 2 * D * K2);
    int* offsets = counts + N_NODES;
    int* srcs    = offsets + N_NODES + 1;
    int* bsum    = srcs + N_EDGES;
    int* bpre    = bsum + 64;

    const int eBlocks = (N_EDGES + 255) / 256;
    const int gemmBlocks = (N_NODES + 31) / 32;

    // CSR (shared by both layers)
    hipMemsetAsync(counts, 0, N_NODES * sizeof(int), stream);
    hist_kernel<<<eBlocks, 256, 0, stream>>>(ei, counts);
    scan_p1<<<NB_SCAN, 256, 0, stream>>>(counts, bsum);
    scan_p2<<<1, 64, 0, stream>>>(bsum, bpre);
    scan_p3<<<NB_SCAN, 256, 0, stream>>>(counts, bpre, offsets);
    build_csr_kernel<<<eBlocks, 256, 0, stream>>>(ei, counts, srcs);

    // operand prep
    convert_x_kernel<<<N_NODES * 16 / 256, 256, 0, stream>>>(x, A);
    prep_w_kernel<<<65536 / 256, 256, 0, stream>>>(Wl1, Wr1, Wl2, Wr2, WT);

    // layer 1: agg -> A[:,0:128]; gemm -> h bf16 into A[:,128:256] (in place, rows disjoint)
    agg_kernel<<<N_NODES / 16, 256, 0, stream>>>(A, offsets, srcs);
    gemm_kernel<true, true><<<gemmBlocks, 64, 0, stream>>>(A, WT, b1, nullptr, A);

    // layer 2: agg over h; gemm -> fp32 d_out
    agg_kernel<<<N_NODES / 16, 256, 0, stream>>>(A, offsets, srcs);
    gemm_kernel<false, false><<<gemmBlocks, 64, 0, stream>>>(A, WT + (size_t)D * K2, b2, out, nullptr);
}

// Round 5
// 224.105 us; speedup vs baseline: 10.5145x; 1.1705x over previous
//
#include <hip/hip_runtime.h>
#include <hip/hip_bf16.h>

#define N_NODES 50000
#define N_EDGES 600000
#define D 128
#define K2 256  // 2*D
#define SCAN_BLK 1024
#define NB_SCAN ((N_NODES + SCAN_BLK - 1) / SCAN_BLK)  // 49

// fused-prep block ranges
#define CVT_BLOCKS  (N_NODES * 16 / 256)                 // 3125
#define HIST_BLOCKS ((N_EDGES + 255) / 256)              // 2344
#define PREPW_BLOCKS (2 * D * K2 / 256)                  // 256
#define PREP_GRID (CVT_BLOCKS + HIST_BLOCKS + PREPW_BLOCKS)

typedef __bf16 bf16x8 __attribute__((ext_vector_type(8)));
typedef float  f32x16 __attribute__((ext_vector_type(16)));

__device__ __forceinline__ unsigned short f32_to_bf16_rne(float f) {
    unsigned int u = __builtin_bit_cast(unsigned int, f);
    unsigned int r = (u + 0x7fffu + ((u >> 16) & 1u)) >> 16;
    return (unsigned short)r;
}
__device__ __forceinline__ unsigned pk2(float lo, float hi) {
    return (unsigned)f32_to_bf16_rne(lo) | ((unsigned)f32_to_bf16_rne(hi) << 16);
}
__device__ __forceinline__ float bfl(unsigned int u) { return __builtin_bit_cast(float, u << 16); }
__device__ __forceinline__ float bfh(unsigned int u) { return __builtin_bit_cast(float, u & 0xffff0000u); }

// ---------- fused prep: x->bf16 A0 | edge histogram | W->WT bf16 ----------
__global__ __launch_bounds__(256) void prep_kernel(
    const float* __restrict__ x, const int* __restrict__ ei,
    const float* __restrict__ Wl1, const float* __restrict__ Wr1,
    const float* __restrict__ Wl2, const float* __restrict__ Wr2,
    unsigned short* __restrict__ A0, unsigned short* __restrict__ WT,
    int* __restrict__ counts)
{
    const int b = blockIdx.x;
    if (b < CVT_BLOCKS) {
        // x [N][128] f32 -> A0 [N][128] bf16; thread = 8 features
        int idx = b * 256 + threadIdx.x;       // 800000 exactly
        int node = idx >> 4, g = idx & 15;
        const float4* xp = (const float4*)(x + (size_t)node * D + g * 8);
        float4 v0 = xp[0], v1 = xp[1];
        uint4 o;
        o.x = pk2(v0.x, v0.y); o.y = pk2(v0.z, v0.w);
        o.z = pk2(v1.x, v1.y); o.w = pk2(v1.z, v1.w);
        ((uint4*)A0)[(size_t)node * 16 + g] = o;
    } else if (b < CVT_BLOCKS + HIST_BLOCKS) {
        int e = (b - CVT_BLOCKS) * 256 + threadIdx.x;
        if (e < N_EDGES) atomicAdd(&counts[ei[N_EDGES + e]], 1);
    } else {
        // WT[layer][n][k]: k<128 -> Wl[k][n], k>=128 -> Wr[k-128][n]
        int idx = (b - CVT_BLOCKS - HIST_BLOCKS) * 256 + threadIdx.x;  // 65536 exactly
        int layer = idx >> 15, rem = idx & 32767;
        int n = rem >> 8, k = rem & 255;
        const float* Wl = layer ? Wl2 : Wl1;
        const float* Wr = layer ? Wr2 : Wr1;
        float v = (k < D) ? Wl[k * D + n] : Wr[(k - D) * D + n];
        WT[((size_t)layer << 15) + n * K2 + k] = f32_to_bf16_rne(v);
    }
}

// ---- scan phase 1: per-block sums (256 thr x 4 elems) ----
__global__ __launch_bounds__(256) void scan_p1(const int* __restrict__ counts,
                                               int* __restrict__ bsum) {
    __shared__ int wsum[4];
    const int tid = threadIdx.x;
    const int lane = tid & 63, wid = tid >> 6;
    int i0 = blockIdx.x * SCAN_BLK + tid * 4;
    int t = 0;
    #pragma unroll
    for (int k = 0; k < 4; ++k) if (i0 + k < N_NODES) t += counts[i0 + k];
    int acc = t;
    #pragma unroll
    for (int d = 1; d < 64; d <<= 1) {
        int v = __shfl_up(acc, d, 64);
        if (lane >= d) acc += v;
    }
    if (lane == 63) wsum[wid] = acc;
    __syncthreads();
    if (tid == 0) bsum[blockIdx.x] = wsum[0] + wsum[1] + wsum[2] + wsum[3];
}

// ---- scan phase 2+3 fused: each block sums its predecessors' bsums itself ----
__global__ __launch_bounds__(256) void scan_p3(int* __restrict__ counts,
                                               const int* __restrict__ bsum,
                                               int* __restrict__ offsets) {
    __shared__ int wsum[4];
    __shared__ int bpre_s;
    const int tid = threadIdx.x;
    const int lane = tid & 63, wid = tid >> 6;
    if (tid < 64) {
        int v = (tid < blockIdx.x) ? bsum[tid] : 0;   // NB_SCAN=49 <= 64
        #pragma unroll
        for (int d = 32; d; d >>= 1) v += __shfl_xor(v, d, 64);
        if (tid == 0) bpre_s = v;
    }
    int i0 = blockIdx.x * SCAN_BLK + tid * 4;
    int c[4];
    int t = 0;
    #pragma unroll
    for (int k = 0; k < 4; ++k) {
        c[k] = (i0 + k < N_NODES) ? counts[i0 + k] : 0;
        t += c[k];
    }
    int acc = t;
    #pragma unroll
    for (int d = 1; d < 64; d <<= 1) {
        int v = __shfl_up(acc, d, 64);
        if (lane >= d) acc += v;
    }
    if (lane == 63) wsum[wid] = acc;
    __syncthreads();
    if (tid == 0) {
        int s = 0;
        #pragma unroll
        for (int w = 0; w < 4; ++w) { int v = wsum[w]; wsum[w] = s; s += v; }
    }
    __syncthreads();
    int excl = bpre_s + wsum[wid] + (acc - t);
    #pragma unroll
    for (int k = 0; k < 4; ++k) {
        if (i0 + k < N_NODES) {
            counts[i0 + k] = excl;              // scatter cursor
            offsets[i0 + k + 1] = excl + c[k];  // segment end
        }
        excl += c[k];
    }
    if (blockIdx.x == 0 && tid == 0) offsets[0] = 0;
}

__global__ __launch_bounds__(256) void build_csr_kernel(const int* __restrict__ ei,
                                                        int* __restrict__ cursor,
                                                        int* __restrict__ sorted_src) {
    int e = blockIdx.x * blockDim.x + threadIdx.x;
    if (e < N_EDGES) {
        int src = ei[e];
        int dst = ei[N_EDGES + e];
        int pos = atomicAdd(&cursor[dst], 1);
        sorted_src[pos] = src;
    }
}

// ---------- fused layer: gather-mean -> LDS A-tile (fragment order) -> MFMA ----------
// Block = 256 thr, 32 nodes. LDS tile As4[(s*2+kg)*32 + m] holds A[m][k],
// k = s*16 + kg*8 + j (j<8). Mean at k<128 (s=0..7), self x at k>=128 (s=8..15).
// GEMM: wave w computes cols [w*32, w*32+32), K=256, 16x MFMA 32x32x16 bf16.
// C/D: col=lane&31, row=(reg&3)+8*(reg>>2)+4*(lane>>5)  [measured m74/m101].
template <bool RELU, bool OUT_BF16>
__global__ __launch_bounds__(256) void layer_kernel(
    const unsigned short* __restrict__ Xin,   // [N][128] bf16
    const int* __restrict__ offsets, const int* __restrict__ srcs,
    const unsigned short* __restrict__ WT,    // [128][256] bf16
    const float* __restrict__ bias,
    unsigned short* __restrict__ Hout,        // layer1: h bf16 [N][128]
    float* __restrict__ outf)                 // layer2: f32 [N][128]
{
    __shared__ uint4 As4[16 * 2 * 32];        // 16 KB
    const int tid = threadIdx.x;
    const int base = blockIdx.x * 32;
    const uint4* X4 = (const uint4*)Xin;      // row stride = 16 uint4

    // ---- gather phase: 8 threads per node ----
    {
        const int m = tid >> 3;               // node slot 0..31
        const int c = tid & 7;                // feature chunk: 16 feats = 2 uint4
        const int node = base + m;
        int beg = 0, end = 0;
        if (node < N_NODES) { beg = offsets[node]; end = offsets[node + 1]; }

        float a[16];
        #pragma unroll
        for (int k = 0; k < 16; ++k) a[k] = 0.0f;

        int e = beg;
        for (; e + 1 < end; e += 2) {
            int s0 = srcs[e], s1 = srcs[e + 1];
            uint4 v0 = X4[(size_t)s0 * 16 + c * 2];
            uint4 v1 = X4[(size_t)s0 * 16 + c * 2 + 1];
            uint4 w0 = X4[(size_t)s1 * 16 + c * 2];
            uint4 w1 = X4[(size_t)s1 * 16 + c * 2 + 1];
            a[0] += bfl(v0.x); a[1] += bfh(v0.x); a[2] += bfl(v0.y); a[3] += bfh(v0.y);
            a[4] += bfl(v0.z); a[5] += bfh(v0.z); a[6] += bfl(v0.w); a[7] += bfh(v0.w);
            a[8] += bfl(v1.x); a[9] += bfh(v1.x); a[10] += bfl(v1.y); a[11] += bfh(v1.y);
            a[12] += bfl(v1.z); a[13] += bfh(v1.z); a[14] += bfl(v1.w); a[15] += bfh(v1.w);
            a[0] += bfl(w0.x); a[1] += bfh(w0.x); a[2] += bfl(w0.y); a[3] += bfh(w0.y);
            a[4] += bfl(w0.z); a[5] += bfh(w0.z); a[6] += bfl(w0.w); a[7] += bfh(w0.w);
            a[8] += bfl(w1.x); a[9] += bfh(w1.x); a[10] += bfl(w1.y); a[11] += bfh(w1.y);
            a[12] += bfl(w1.z); a[13] += bfh(w1.z); a[14] += bfl(w1.w); a[15] += bfh(w1.w);
        }
        if (e < end) {
            int s0 = srcs[e];
            uint4 v0 = X4[(size_t)s0 * 16 + c * 2];
            uint4 v1 = X4[(size_t)s0 * 16 + c * 2 + 1];
            a[0] += bfl(v0.x); a[1] += bfh(v0.x); a[2] += bfl(v0.y); a[3] += bfh(v0.y);
            a[4] += bfl(v0.z); a[5] += bfh(v0.z); a[6] += bfl(v0.w); a[7] += bfh(v0.w);
            a[8] += bfl(v1.x); a[9] += bfh(v1.x); a[10] += bfl(v1.y); a[11] += bfh(v1.y);
            a[12] += bfl(v1.z); a[13] += bfh(v1.z); a[14] += bfl(v1.w); a[15] += bfh(v1.w);
        }
        float inv = 1.0f / fmaxf((float)(end - beg), 1.0f);
        uint4 o0, o1;
        o0.x = pk2(a[0] * inv, a[1] * inv);  o0.y = pk2(a[2] * inv, a[3] * inv);
        o0.z = pk2(a[4] * inv, a[5] * inv);  o0.w = pk2(a[6] * inv, a[7] * inv);
        o1.x = pk2(a[8] * inv, a[9] * inv);  o1.y = pk2(a[10] * inv, a[11] * inv);
        o1.z = pk2(a[12] * inv, a[13] * inv); o1.w = pk2(a[14] * inv, a[15] * inv);
        // mean half: k = c*16 .. c*16+15 -> s=c, kg=0/1
        As4[(c * 2 + 0) * 32 + m] = o0;
        As4[(c * 2 + 1) * 32 + m] = o1;
        // x half: k = 128 + c*16 .. -> s=8+c, kg=0/1 (straight bf16 copy)
        uint4 x0 = {0, 0, 0, 0}, x1 = {0, 0, 0, 0};
        if (node < N_NODES) {
            x0 = X4[(size_t)node * 16 + c * 2];
            x1 = X4[(size_t)node * 16 + c * 2 + 1];
        }
        As4[((8 + c) * 2 + 0) * 32 + m] = x0;
        As4[((8 + c) * 2 + 1) * 32 + m] = x1;
    }
    __syncthreads();

    // ---- GEMM phase ----
    const int l = tid & 63;
    const int w = tid >> 6;
    const int m = l & 31;
    const int kg = l >> 5;
    const int col = w * 32 + m;
    const uint4* bp = (const uint4*)(WT + (size_t)col * K2 + kg * 8);
    const bf16x8* afrag = (const bf16x8*)As4;

    f32x16 acc = {};
    #pragma unroll
    for (int s = 0; s < 16; ++s) {
        bf16x8 a = afrag[(s * 2 + kg) * 32 + m];
        bf16x8 b = __builtin_bit_cast(bf16x8, bp[s * 2]);
        acc = __builtin_amdgcn_mfma_f32_32x32x16_bf16(a, b, acc, 0, 0, 0);
    }

    const float bc = bias[col];
    const int halfadd = kg * 4;
    #pragma unroll
    for (int r = 0; r < 16; ++r) {
        int rw = base + (r & 3) + 8 * (r >> 2) + halfadd;
        if (rw < N_NODES) {
            float v = acc[r] + bc;
            if (RELU) v = fmaxf(v, 0.0f);
            if (OUT_BF16) Hout[(size_t)rw * D + col] = f32_to_bf16_rne(v);
            else outf[(size_t)rw * D + col] = v;
        }
    }
}

extern "C" void kernel_launch(void* const* d_in, const int* in_sizes, int n_in,
                              void* d_out, int out_size, void* d_ws, size_t ws_size,
                              hipStream_t stream) {
    const float* x   = (const float*)d_in[0];
    const int*   ei  = (const int*)d_in[1];
    const float* Wl1 = (const float*)d_in[2];
    const float* Wr1 = (const float*)d_in[3];
    const float* b1  = (const float*)d_in[4];
    const float* Wl2 = (const float*)d_in[5];
    const float* Wr2 = (const float*)d_in[6];
    const float* b2  = (const float*)d_in[7];
    float* out = (float*)d_out;

    // ws: A0 [N][128] bf16 | A1 [N][128] bf16 | WT [2][128][256] bf16 |
    //     counts [N] | offsets [N+1] | srcs [E] | bsum [64]
    unsigned short* A0 = (unsigned short*)d_ws;
    unsigned short* A1 = A0 + (size_t)N_NODES * D;
    unsigned short* WT = A1 + (size_t)N_NODES * D;
    int* counts  = (int*)(WT + 2 * D * K2);
    int* offsets = counts + N_NODES;
    int* srcs    = offsets + N_NODES + 1;
    int* bsum    = srcs + N_EDGES;

    const int layerBlocks = (N_NODES + 31) / 32;  // 1563

    hipMemsetAsync(counts, 0, N_NODES * sizeof(int), stream);
    prep_kernel<<<PREP_GRID, 256, 0, stream>>>(x, ei, Wl1, Wr1, Wl2, Wr2, A0, WT, counts);
    scan_p1<<<NB_SCAN, 256, 0, stream>>>(counts, bsum);
    scan_p3<<<NB_SCAN, 256, 0, stream>>>(counts, bsum, offsets);
    build_csr_kernel<<<HIST_BLOCKS, 256, 0, stream>>>(ei, counts, srcs);

    layer_kernel<true, true><<<layerBlocks, 256, 0, stream>>>(
        A0, offsets, srcs, WT, b1, A1, nullptr);
    layer_kernel<false, false><<<layerBlocks, 256, 0, stream>>>(
        A1, offsets, srcs, WT + (size_t)D * K2, b2, nullptr, out);
}